// Round 6
// baseline (1107.665 us; speedup 1.0000x reference)
//
#include <hip/hip_runtime.h>

#define T_STEPS 1000
#define BATCH   256
#define NHID    200
#define ROWF    204      // floats per LDS row: 200 weights + W2[i] + 3 zero pad
#define BETA_C  0.85f
#define THR_C   1.0f
#define SENT    (1ull << 50)

// Row i of WT2 holds, at float offset l*4+k (l<50,k<4): Wrec[(l+50k)][i],
// and at offset 200: W2[i]. Lane l does ONE ds_read_b128 per firing neuron i.
// Lane 50's float4 starts at offset 200 -> .x = W2[i], so its rec0
// accumulates cur2 for free, in the same ascending sparse order.

__launch_bounds__(64, 1)
__global__ void rsnn_kernel(const float* __restrict__ X,
                            const float* __restrict__ W1,
                            const float* __restrict__ b1,
                            const float* __restrict__ Wrec,
                            const float* __restrict__ brec,
                            const float* __restrict__ W2,
                            const float* __restrict__ b2,
                            float* __restrict__ out_cur2,
                            float* __restrict__ out_spk) {
#pragma clang fp contract(off)
    __shared__ float WT2[40852];   // 163,408 B

    const int l = threadIdx.x;
    const int b = blockIdx.x;

    // ---- stage Wrec (permuted transpose) + W2 into LDS; zero all pads ----
    for (int idx = l; idx < NHID * NHID; idx += 64) {
        int r  = idx / NHID;            // Wrec row  (output neuron)
        int i  = idx - r * NHID;        // Wrec col  (source neuron)
        int lo = r % 50, k = r / 50;
        WT2[i * ROWF + lo * 4 + k] = Wrec[idx];
    }
    for (int i = l; i < NHID; i += 64) {
        WT2[i * ROWF + 200] = W2[i];
        WT2[i * ROWF + 201] = 0.f;
        WT2[i * ROWF + 202] = 0.f;
        WT2[i * ROWF + 203] = 0.f;
    }
    for (int i = 40800 + l; i < 40852; i += 64) WT2[i] = 0.f;
    __syncthreads();

    const int lc = (l < 50) ? l : 49;
    float w1r[4][3], b1r[4], brr[4];
#pragma unroll
    for (int k = 0; k < 4; ++k) {
        int i = lc + 50 * k;
        w1r[k][0] = W1[i * 3 + 0];
        w1r[k][1] = W1[i * 3 + 1];
        w1r[k][2] = W1[i * 3 + 2];
        b1r[k] = b1[i];
        brr[k] = brec[i];
    }
    const float b2v = b2[0];

    float mem0 = 0.f, mem1 = 0.f, mem2 = 0.f, mem3 = 0.f;
    unsigned long long bm0 = 0, bm1 = 0, bm2 = 0, bm3 = 0;

    const float* xp = X + (size_t)b * 3;
    float x0 = xp[0], x1 = xp[1], x2 = xp[2];

    float*       spk_base = out_spk + (size_t)b * NHID + lc;
    const float* ldsrow   = WT2 + (size_t)l * 4;

    // ---- persistent 3-deep pipeline registers (always finite) ----
    float4 vA0{0,0,0,0}, vA1{0,0,0,0}, vA2{0,0,0,0}, vA3{0,0,0,0};
    float4 vB0{0,0,0,0}, vB1{0,0,0,0}, vB2{0,0,0,0}, vB3{0,0,0,0};
    float4 vC0{0,0,0,0}, vC1{0,0,0,0}, vC2{0,0,0,0}, vC3{0,0,0,0};
    float  sA0, sA1, sA2, sA3, sB0, sB1, sB2, sB3, sC0, sC1, sC2, sC3;

// advance the flattened word stream when current word exhausted
#define ADV                                                            \
    if (m == 0ull) {                                                   \
        if (q1)      { m = q1; basef =  50u * ROWF; q1 = 0; }          \
        else if (q2) { m = q2; basef = 100u * ROWF; q2 = 0; }          \
        else if (q3) { m = q3; basef = 150u * ROWF; q3 = 0; }          \
        else         { done = true; basef = 0u; }                      \
    }

// one slot: sentinel keeps ctz defined; clamp keeps the gated load in-bounds
#define SLOTX(SS, OFF)                                                 \
    ADV                                                                \
    SS = done ? 0.f : 1.f;                                             \
    {                                                                  \
        unsigned long long mm = m | SENT;                              \
        int r = __builtin_ctzll(mm);                                   \
        int ii = r > 49 ? 49 : r;                                      \
        OFF = basef + (unsigned)ii * ROWF;                             \
    }                                                                  \
    m &= m - 1;

#define ISSUE(P)                                                       \
    SLOTX(s##P##0, o0) SLOTX(s##P##1, o1)                              \
    SLOTX(s##P##2, o2) SLOTX(s##P##3, o3)                              \
    v##P##0 = *(const float4*)(ldsrow + o0);                           \
    v##P##1 = *(const float4*)(ldsrow + o1);                           \
    v##P##2 = *(const float4*)(ldsrow + o2);                           \
    v##P##3 = *(const float4*)(ldsrow + o3);

// fma with sel in {0,1} is bit-exact (0*finite no-op / 1*w == +w)
#define ACC1(P, K)                                                     \
    rec0 = fmaf(s##P##K, v##P##K.x, rec0);                             \
    rec1 = fmaf(s##P##K, v##P##K.y, rec1);                             \
    rec2 = fmaf(s##P##K, v##P##K.z, rec2);                             \
    rec3 = fmaf(s##P##K, v##P##K.w, rec3);

#define ACCG(P) ACC1(P, 0) ACC1(P, 1) ACC1(P, 2) ACC1(P, 3)

    for (int t = 0; t < T_STEPS; ++t) {
        // prefetch next step's input (used one iteration later)
        int   tn  = (t + 1 < T_STEPS) ? t + 1 : t;
        float nx0 = xp[(size_t)tn * BATCH * 3 + 0];
        float nx1 = xp[(size_t)tn * BATCH * 3 + 1];
        float nx2 = xp[(size_t)tn * BATCH * 3 + 2];

        // ---- flattened-stream state (wave-uniform) ----
        unsigned long long m = bm0, q1 = bm1, q2 = bm2, q3 = bm3;
        unsigned basef = 0;
        bool     done  = false;
        unsigned o0, o1, o2, o3;
        float rec0 = 0.f, rec1 = 0.f, rec2 = 0.f, rec3 = 0.f;

        // reset gates; stale v-regs are finite -> gated fma is exact no-op
        sA0 = sA1 = sA2 = sA3 = 0.f;
        sB0 = sB1 = sB2 = sB3 = 0.f;
        sC0 = sC1 = sC2 = sC3 = 0.f;

        // ---- 3-phase rotating gather pipeline (each phase = own BB) ----
    PH_A:
        if (done) goto DR_A;
        ACCG(A) ISSUE(A)
    PH_B:
        if (done) goto DR_B;
        ACCG(B) ISSUE(B)
    PH_C:
        if (done) goto DR_C;
        ACCG(C) ISSUE(C)
        goto PH_A;
    DR_A:
        ACCG(A) ACCG(B) ACCG(C) goto GDONE;
    DR_B:
        ACCG(B) ACCG(C) ACCG(A) goto GDONE;
    DR_C:
        ACCG(C) ACCG(A) ACCG(B) goto GDONE;
    GDONE: ;

        // lane 50's rec0 = sum of W2 over firing set of step t-1 = cur2_{t-1}
        if (t > 0 && l == 50)
            out_cur2[(size_t)(t - 1) * BATCH + b] = rec0 + b2v;

        // ---- membrane update (numpy op/rounding order preserved) ----
        float c0 = fmaf(x2, w1r[0][2], fmaf(x1, w1r[0][1], x0 * w1r[0][0])) + b1r[0];
        float c1 = fmaf(x2, w1r[1][2], fmaf(x1, w1r[1][1], x0 * w1r[1][0])) + b1r[1];
        float c2 = fmaf(x2, w1r[2][2], fmaf(x1, w1r[2][1], x0 * w1r[2][0])) + b1r[2];
        float c3 = fmaf(x2, w1r[3][2], fmaf(x1, w1r[3][1], x0 * w1r[3][0])) + b1r[3];

        float ba0 = ((BETA_C * mem0 + c0) + rec0) + brr[0];
        float ba1 = ((BETA_C * mem1 + c1) + rec1) + brr[1];
        float ba2 = ((BETA_C * mem2 + c2) + rec2) + brr[2];
        float ba3 = ((BETA_C * mem3 + c3) + rec3) + brr[3];

        float nm0 = (mem0 > THR_C) ? 0.f : ba0;
        float nm1 = (mem1 > THR_C) ? 0.f : ba1;
        float nm2 = (mem2 > THR_C) ? 0.f : ba2;
        float nm3 = (mem3 > THR_C) ? 0.f : ba3;

        float sp0 = (nm0 > THR_C) ? 1.f : 0.f;
        float sp1 = (nm1 > THR_C) ? 1.f : 0.f;
        float sp2 = (nm2 > THR_C) ? 1.f : 0.f;
        float sp3 = (nm3 > THR_C) ? 1.f : 0.f;

        mem0 = nm0; mem1 = nm1; mem2 = nm2; mem3 = nm3;

        // ---- record spikes (fire-and-forget coalesced stores, no barrier) ----
        if (l < 50) {
            float* sb = spk_base + (size_t)t * BATCH * NHID;
            sb[0]   = sp0;
            sb[50]  = sp1;
            sb[100] = sp2;
            sb[150] = sp3;
        }

        // ---- publish wave-uniform spike masks for next step ----
        bm0 = __ballot((l < 50) && (sp0 > 0.5f));
        bm1 = __ballot((l < 50) && (sp1 > 0.5f));
        bm2 = __ballot((l < 50) && (sp2 > 0.5f));
        bm3 = __ballot((l < 50) && (sp3 > 0.5f));

        x0 = nx0; x1 = nx1; x2 = nx2;
    }

    // ---- epilogue: cur2_{T-1} from final spike masks (same ascending order) ----
    {
        float c2f = 0.f;
        unsigned long long ms0 = bm0, ms1 = bm1, ms2 = bm2, ms3 = bm3;
#define C2_WORD(M, BASE)                                               \
        {                                                              \
            unsigned long long mm2 = (M);                              \
            while (mm2) {                                              \
                int i = __builtin_ctzll(mm2) + (BASE); mm2 &= mm2 - 1; \
                c2f += WT2[i * ROWF + 200];                            \
            }                                                          \
        }
        C2_WORD(ms0, 0) C2_WORD(ms1, 50) C2_WORD(ms2, 100) C2_WORD(ms3, 150)
        if (l == 50)
            out_cur2[(size_t)(T_STEPS - 1) * BATCH + b] = c2f + b2v;
#undef C2_WORD
    }
}

extern "C" void kernel_launch(void* const* d_in, const int* in_sizes, int n_in,
                              void* d_out, int out_size, void* d_ws, size_t ws_size,
                              hipStream_t stream) {
    const float* X    = (const float*)d_in[0];
    const float* W1   = (const float*)d_in[1];
    const float* b1   = (const float*)d_in[2];
    const float* Wrec = (const float*)d_in[3];
    const float* brec = (const float*)d_in[4];
    const float* W2   = (const float*)d_in[5];
    const float* b2   = (const float*)d_in[6];

    float* out_cur2 = (float*)d_out;                            // [T,B,1] flat
    float* out_spk  = (float*)d_out + (size_t)T_STEPS * BATCH;  // [T,B,200] flat

    rsnn_kernel<<<BATCH, 64, 0, stream>>>(X, W1, b1, Wrec, brec, W2, b2,
                                          out_cur2, out_spk);
}

// Round 7
// 1071.497 us; speedup vs baseline: 1.0338x; 1.0338x over previous
//
#include <hip/hip_runtime.h>

#define T_STEPS 1000
#define BATCH   256
#define NHID    200
#define ROWF    204      // floats per LDS row (816 B): 200 weights + W2[i] + 3 pad
#define BETA_C  0.85f
#define THR_C   1.0f
#define WPB     8        // waves (= batch elements) per block
#define BLOCKT  (WPB * 64)

// Row i of WT2 holds, at float offset l*4+k (l<50,k<4): Wrec[(l+50k)][i],
// and at offset 200: W2[i]. Lane l does ONE ds_read_b128 per firing neuron i,
// getting the 4 weights for its output neurons {l, l+50, l+100, l+150}.
// Lane 50's b128 starts at offset 200 -> v.x = W2[i], so its rec0
// accumulates cur2 for free, in ascending-i order.
//
// 8 waves share the LDS weight image; each wave is an independent batch
// element (own masks, own ballots, no barriers after staging). 2 waves/SIMD
// interleave to hide LDS latency (TLP instead of source-level pipelining).

__launch_bounds__(BLOCKT, 1)
__global__ void rsnn_kernel(const float* __restrict__ X,
                            const float* __restrict__ W1,
                            const float* __restrict__ b1,
                            const float* __restrict__ Wrec,
                            const float* __restrict__ brec,
                            const float* __restrict__ W2,
                            const float* __restrict__ b2,
                            float* __restrict__ out_cur2,
                            float* __restrict__ out_spk) {
#pragma clang fp contract(off)
    __shared__ float WT2[40852];   // 163,408 B  (1 block/CU)

    const int tid  = threadIdx.x;
    const int l    = tid & 63;              // lane in wave
    const int wave = tid >> 6;              // wave id in block
    const int b    = blockIdx.x * WPB + wave;   // batch element

    // ---- stage Wrec (permuted transpose) + W2 into LDS (all 512 threads) ----
    for (int idx = tid; idx < NHID * NHID; idx += BLOCKT) {
        int r  = idx / NHID;            // Wrec row  (output neuron)
        int i  = idx - r * NHID;        // Wrec col  (source neuron)
        int lo = r % 50, k = r / 50;
        WT2[i * ROWF + lo * 4 + k] = Wrec[idx];
    }
    for (int i = tid; i < NHID; i += BLOCKT) {
        WT2[i * ROWF + 200] = W2[i];
        WT2[i * ROWF + 201] = 0.f;
        WT2[i * ROWF + 202] = 0.f;
        WT2[i * ROWF + 203] = 0.f;
    }
    for (int i = 40800 + tid; i < 40852; i += BLOCKT) WT2[i] = 0.f;
    __syncthreads();   // only barrier in the kernel

    const int lc = (l < 50) ? l : 49;
    float w1r[4][3], b1r[4], brr[4];
#pragma unroll
    for (int k = 0; k < 4; ++k) {
        int i = lc + 50 * k;
        w1r[k][0] = W1[i * 3 + 0];
        w1r[k][1] = W1[i * 3 + 1];
        w1r[k][2] = W1[i * 3 + 2];
        b1r[k] = b1[i];
        brr[k] = brec[i];
    }
    const float b2v = b2[0];

    float mem0 = 0.f, mem1 = 0.f, mem2 = 0.f, mem3 = 0.f;
    unsigned long long bm0 = 0, bm1 = 0, bm2 = 0, bm3 = 0;

    const float* xp = X + (size_t)b * 3;
    float x0 = xp[0], x1 = xp[1], x2 = xp[2];

    float*       spk_base = out_spk + (size_t)b * NHID + lc;
    const float* ldsrow   = WT2 + (size_t)l * 4;

#define REC_WORD(MASK, BASE)                                                          \
    {                                                                                 \
        unsigned long long m = (MASK);                                                \
        while (m) {                                                                   \
            int i0 = __builtin_ctzll(m); m &= m - 1;                                  \
            bool h1 = m != 0; int i1 = h1 ? __builtin_ctzll(m) : i0; if (h1) m &= m - 1; \
            bool h2 = m != 0; int i2 = h2 ? __builtin_ctzll(m) : i0; if (h2) m &= m - 1; \
            bool h3 = m != 0; int i3 = h3 ? __builtin_ctzll(m) : i0; if (h3) m &= m - 1; \
            const float4 v0 = *(const float4*)(ldsrow + (i0 + (BASE)) * ROWF);        \
            const float4 v1 = *(const float4*)(ldsrow + (i1 + (BASE)) * ROWF);        \
            const float4 v2 = *(const float4*)(ldsrow + (i2 + (BASE)) * ROWF);        \
            const float4 v3 = *(const float4*)(ldsrow + (i3 + (BASE)) * ROWF);        \
            rec0 += v0.x; rec1 += v0.y; rec2 += v0.z; rec3 += v0.w;                   \
            if (h1) { rec0 += v1.x; rec1 += v1.y; rec2 += v1.z; rec3 += v1.w; }       \
            if (h2) { rec0 += v2.x; rec1 += v2.y; rec2 += v2.z; rec3 += v2.w; }       \
            if (h3) { rec0 += v3.x; rec1 += v3.y; rec2 += v3.z; rec3 += v3.w; }       \
        }                                                                             \
    }

    for (int t = 0; t < T_STEPS; ++t) {
        // prefetch next step's input (used one iteration later)
        int   tn  = (t + 1 < T_STEPS) ? t + 1 : t;
        float nx0 = xp[(size_t)tn * BATCH * 3 + 0];
        float nx1 = xp[(size_t)tn * BATCH * 3 + 1];
        float nx2 = xp[(size_t)tn * BATCH * 3 + 2];

        // ---- sparse recurrent input from previous step's spikes ----
        float rec0 = 0.f, rec1 = 0.f, rec2 = 0.f, rec3 = 0.f;
        REC_WORD(bm0, 0)
        REC_WORD(bm1, 50)
        REC_WORD(bm2, 100)
        REC_WORD(bm3, 150)

        // lane 50's rec0 = sum of W2 over firing set of step t-1 = cur2_{t-1}
        if (t > 0 && l == 50)
            out_cur2[(size_t)(t - 1) * BATCH + b] = rec0 + b2v;

        // ---- membrane update (numpy op/rounding order preserved) ----
        float c0 = fmaf(x2, w1r[0][2], fmaf(x1, w1r[0][1], x0 * w1r[0][0])) + b1r[0];
        float c1 = fmaf(x2, w1r[1][2], fmaf(x1, w1r[1][1], x0 * w1r[1][0])) + b1r[1];
        float c2 = fmaf(x2, w1r[2][2], fmaf(x1, w1r[2][1], x0 * w1r[2][0])) + b1r[2];
        float c3 = fmaf(x2, w1r[3][2], fmaf(x1, w1r[3][1], x0 * w1r[3][0])) + b1r[3];

        float ba0 = ((BETA_C * mem0 + c0) + rec0) + brr[0];
        float ba1 = ((BETA_C * mem1 + c1) + rec1) + brr[1];
        float ba2 = ((BETA_C * mem2 + c2) + rec2) + brr[2];
        float ba3 = ((BETA_C * mem3 + c3) + rec3) + brr[3];

        float nm0 = (mem0 > THR_C) ? 0.f : ba0;
        float nm1 = (mem1 > THR_C) ? 0.f : ba1;
        float nm2 = (mem2 > THR_C) ? 0.f : ba2;
        float nm3 = (mem3 > THR_C) ? 0.f : ba3;

        float sp0 = (nm0 > THR_C) ? 1.f : 0.f;
        float sp1 = (nm1 > THR_C) ? 1.f : 0.f;
        float sp2 = (nm2 > THR_C) ? 1.f : 0.f;
        float sp3 = (nm3 > THR_C) ? 1.f : 0.f;

        mem0 = nm0; mem1 = nm1; mem2 = nm2; mem3 = nm3;

        // ---- record spikes (fire-and-forget coalesced stores, no barrier) ----
        if (l < 50) {
            float* sb = spk_base + (size_t)t * BATCH * NHID;
            sb[0]   = sp0;
            sb[50]  = sp1;
            sb[100] = sp2;
            sb[150] = sp3;
        }

        // ---- publish wave-local spike masks for next step ----
        bm0 = __ballot((l < 50) && (sp0 > 0.5f));
        bm1 = __ballot((l < 50) && (sp1 > 0.5f));
        bm2 = __ballot((l < 50) && (sp2 > 0.5f));
        bm3 = __ballot((l < 50) && (sp3 > 0.5f));

        x0 = nx0; x1 = nx1; x2 = nx2;
    }

    // ---- epilogue: cur2_{T-1} from final spike masks (same ascending order) ----
    {
        float c2f = 0.f;
        unsigned long long ms0 = bm0, ms1 = bm1, ms2 = bm2, ms3 = bm3;
#define C2_WORD(M, BASE)                                               \
        {                                                              \
            unsigned long long mm = (M);                               \
            while (mm) {                                               \
                int i = __builtin_ctzll(mm) + (BASE); mm &= mm - 1;    \
                c2f += WT2[i * ROWF + 200];                            \
            }                                                          \
        }
        C2_WORD(ms0, 0) C2_WORD(ms1, 50) C2_WORD(ms2, 100) C2_WORD(ms3, 150)
        if (l == 50)
            out_cur2[(size_t)(T_STEPS - 1) * BATCH + b] = c2f + b2v;
#undef C2_WORD
    }
#undef REC_WORD
}

extern "C" void kernel_launch(void* const* d_in, const int* in_sizes, int n_in,
                              void* d_out, int out_size, void* d_ws, size_t ws_size,
                              hipStream_t stream) {
    const float* X    = (const float*)d_in[0];
    const float* W1   = (const float*)d_in[1];
    const float* b1   = (const float*)d_in[2];
    const float* Wrec = (const float*)d_in[3];
    const float* brec = (const float*)d_in[4];
    const float* W2   = (const float*)d_in[5];
    const float* b2   = (const float*)d_in[6];

    float* out_cur2 = (float*)d_out;                            // [T,B,1] flat
    float* out_spk  = (float*)d_out + (size_t)T_STEPS * BATCH;  // [T,B,200] flat

    rsnn_kernel<<<BATCH / WPB, BLOCKT, 0, stream>>>(X, W1, b1, Wrec, brec, W2, b2,
                                                    out_cur2, out_spk);
}